// Round 1
// baseline (618.899 us; speedup 1.0000x reference)
//
#include <hip/hip_runtime.h>

// out[b,n,d] = sum_t vol[b,n,t] * M[d,t] + bias[d]
// M[d,t] = sum_{m<64} W[d][m]*cos(2pi m t/512) - W[d][64+m]*sin(2pi m t/512)
// GEMM: C (131072 x 512) = A (131072 x 512) * B^T (512 x 512) + bias
// B split into bf16 hi/lo (precomputed), A split on the fly; 3 MFMA GEMMs.

typedef float f32x4 __attribute__((ext_vector_type(4)));
typedef short s16x8 __attribute__((ext_vector_type(8)));
typedef unsigned short u16;

__device__ __forceinline__ u16 f32_to_bf16_rne(float x) {
  unsigned u = __builtin_bit_cast(unsigned, x);
  unsigned r = 0x7FFFu + ((u >> 16) & 1u);
  return (u16)((u + r) >> 16);
}
__device__ __forceinline__ float bf16_to_f32(u16 h) {
  unsigned u = ((unsigned)h) << 16;
  return __builtin_bit_cast(float, u);
}

// ---------------- Kernel 1: build M = W * F, split into bf16 hi/lo ----------
// grid (2, 512), block 256. t = bx*256+tid, d = by.
__global__ void build_M_kernel(const float* __restrict__ W,
                               u16* __restrict__ Mh, u16* __restrict__ Ml) {
  __shared__ float Wrow[128];
  const int d = blockIdx.y;
  const int tid = threadIdx.x;
  if (tid < 128) Wrow[tid] = W[d * 128 + tid];
  __syncthreads();
  const int t = blockIdx.x * 256 + tid;
  float acc = 0.f;
#pragma unroll 8
  for (int m = 0; m < 64; ++m) {
    int r = (m * t) & 511;                  // exact: period 512
    float th = (float)r * 0.01227184630308513f; // 2*pi/512
    float s, c;
    __sincosf(th, &s, &c);
    acc = fmaf(Wrow[m], c, acc);
    acc = fmaf(-Wrow[64 + m], s, acc);
  }
  u16 h = f32_to_bf16_rne(acc);
  u16 l = f32_to_bf16_rne(acc - bf16_to_f32(h));
  Mh[d * 512 + t] = h;
  Ml[d * 512 + t] = l;
}

// ---------------- Kernel 2: split-bf16 MFMA GEMM ----------------------------
// Tile: BM=128, BN=128, BK=32. 256 threads = 4 waves (2x2 of 64x64).
// LDS: [2 bufs][Ah, Al, Bh, Bl][128*32] u16 = 64 KB -> 2 blocks/CU.
__global__ __launch_bounds__(256, 2) void gemm_kernel(
    const float* __restrict__ A,   // vol: 131072 x 512 (f32)
    const u16* __restrict__ Bh,    // Mh:  512 x 512 (bf16 bits, d-major)
    const u16* __restrict__ Bl,    // Ml
    const float* __restrict__ bias,
    float* __restrict__ C) {       // 131072 x 512 (f32)
  __shared__ u16 lds[2][4][128 * 32];

  const int tid = threadIdx.x;
  const int lane = tid & 63;
  const int wid = tid >> 6;
  const int wm = wid >> 1;
  const int wn = wid & 1;

  // XCD-aware swizzle: 4 col-blocks of a row-block adjacent on one XCD so the
  // shared A-tile stays L2-resident (assumes dispatch round-robins b%8).
  const int b = blockIdx.x;            // 4096 blocks
  const int xcd = b & 7;
  const int s = b >> 3;                // 0..511
  const int rb = xcd * 128 + (s >> 2); // 0..1023
  const int cb = s & 3;                // 0..3
  const int row0 = rb * 128;
  const int col0 = cb * 128;

  f32x4 acc[4][4];
#pragma unroll
  for (int m = 0; m < 4; ++m)
#pragma unroll
    for (int n = 0; n < 4; ++n)
      acc[m][n] = (f32x4){0.f, 0.f, 0.f, 0.f};

  float4 areg[4];
  s16x8 breg[4];

  auto stage_load = [&](int ks) {
    const int k0 = ks * 32;
#pragma unroll
    for (int i = 0; i < 4; ++i) {
      int idx = i * 256 + tid;         // 0..1023 float4 slots
      int r = idx >> 3, c4 = idx & 7;  // row 0..127, float4-col 0..7
      areg[i] = *(const float4*)(A + (size_t)(row0 + r) * 512 + k0 + c4 * 4);
    }
#pragma unroll
    for (int j = 0; j < 2; ++j) {
      int c = j * 256 + tid;           // 0..511 16B chunks
      int dd = c >> 2, kc = (c & 3) * 8;
      breg[j]     = *(const s16x8*)(Bh + (size_t)(col0 + dd) * 512 + k0 + kc);
      breg[2 + j] = *(const s16x8*)(Bl + (size_t)(col0 + dd) * 512 + k0 + kc);
    }
  };

  auto stage_write = [&](int buf) {
#pragma unroll
    for (int i = 0; i < 4; ++i) {
      int idx = i * 256 + tid;
      int r = idx >> 3, c4 = idx & 7;
      float vs[4] = {areg[i].x, areg[i].y, areg[i].z, areg[i].w};
      ushort4 hv, lv;
      u16 h;
      h = f32_to_bf16_rne(vs[0]); hv.x = h; lv.x = f32_to_bf16_rne(vs[0] - bf16_to_f32(h));
      h = f32_to_bf16_rne(vs[1]); hv.y = h; lv.y = f32_to_bf16_rne(vs[1] - bf16_to_f32(h));
      h = f32_to_bf16_rne(vs[2]); hv.z = h; lv.z = f32_to_bf16_rne(vs[2] - bf16_to_f32(h));
      h = f32_to_bf16_rne(vs[3]); hv.w = h; lv.w = f32_to_bf16_rne(vs[3] - bf16_to_f32(h));
      *reinterpret_cast<ushort4*>(&lds[buf][0][r * 32 + c4 * 4]) = hv;
      *reinterpret_cast<ushort4*>(&lds[buf][1][r * 32 + c4 * 4]) = lv;
    }
#pragma unroll
    for (int j = 0; j < 2; ++j) {
      int c = j * 256 + tid;
      *reinterpret_cast<s16x8*>(&lds[buf][2][c * 8]) = breg[j];
      *reinterpret_cast<s16x8*>(&lds[buf][3][c * 8]) = breg[2 + j];
    }
  };

  auto compute = [&](int buf) {
    const int rr = lane & 15;
    const int kg = lane >> 4;
    s16x8 ah[4], al[4], bhf[4], blf[4];
#pragma unroll
    for (int m = 0; m < 4; ++m) {
      int off = (wm * 64 + m * 16 + rr) * 32 + kg * 8;
      ah[m] = *(const s16x8*)&lds[buf][0][off];
      al[m] = *(const s16x8*)&lds[buf][1][off];
    }
#pragma unroll
    for (int n = 0; n < 4; ++n) {
      int off = (wn * 64 + n * 16 + rr) * 32 + kg * 8;
      bhf[n] = *(const s16x8*)&lds[buf][2][off];
      blf[n] = *(const s16x8*)&lds[buf][3][off];
    }
#pragma unroll
    for (int m = 0; m < 4; ++m)
#pragma unroll
      for (int n = 0; n < 4; ++n) {
        acc[m][n] = __builtin_amdgcn_mfma_f32_16x16x32_bf16(ah[m], bhf[n], acc[m][n], 0, 0, 0);
        acc[m][n] = __builtin_amdgcn_mfma_f32_16x16x32_bf16(al[m], bhf[n], acc[m][n], 0, 0, 0);
        acc[m][n] = __builtin_amdgcn_mfma_f32_16x16x32_bf16(ah[m], blf[n], acc[m][n], 0, 0, 0);
      }
  };

  // prologue: stage K-step 0 into buf0
  stage_load(0);
  stage_write(0);

  for (int ks = 0; ks < 16; ++ks) {
    const int buf = ks & 1;
    __syncthreads();                 // staging of buf complete (vm+lgkm drain)
    if (ks < 15) stage_load(ks + 1); // issue next-tile global loads early
    compute(buf);                    // ds_read frags + 48 MFMA (latency cover)
    if (ks < 15) stage_write(buf ^ 1); // cvt + ds_write after compute
  }

  // epilogue: bias + store (C/D map: col = lane&15, row = (lane>>4)*4 + reg)
  const int rr = lane & 15;
  const int kg = lane >> 4;
#pragma unroll
  for (int n = 0; n < 4; ++n) {
    int ccol = col0 + wn * 64 + n * 16 + rr;
    float bv = bias[ccol];
#pragma unroll
    for (int m = 0; m < 4; ++m) {
      int r0 = row0 + wm * 64 + m * 16 + kg * 4;
#pragma unroll
      for (int j = 0; j < 4; ++j) {
        C[(size_t)(r0 + j) * 512 + ccol] = acc[m][n][j] + bv;
      }
    }
  }
}

extern "C" void kernel_launch(void* const* d_in, const int* in_sizes, int n_in,
                              void* d_out, int out_size, void* d_ws, size_t ws_size,
                              hipStream_t stream) {
  const float* vol = (const float*)d_in[0]; // 64*2048*512
  const float* W   = (const float*)d_in[1]; // 512*128
  const float* bia = (const float*)d_in[2]; // 512
  float* out = (float*)d_out;               // 64*2048*512

  u16* Mh = (u16*)d_ws;          // 512*512 bf16 hi
  u16* Ml = Mh + 512 * 512;      // 512*512 bf16 lo  (1 MB total scratch)

  dim3 g1(2, 512);
  build_M_kernel<<<g1, 256, 0, stream>>>(W, Mh, Ml);
  gemm_kernel<<<4096, 256, 0, stream>>>(vol, Mh, Ml, bia, out);
}